// Round 6
// baseline (181.859 us; speedup 1.0000x reference)
//
#include <hip/hip_runtime.h>
#include <hip/hip_bf16.h>

// GraphAttentionLayer on MI355X. fp32 I/O, bf16 MFMA internally.
// e[b,i,j] = leakyrelu(s1_i + s2_j), softmax over j, out = elu(attn @ Wh).
// Bound M2_UB = 8 >= max s2 (s2 sigma ~0.9):
//   x_i = s1_i + 8; m_i = max(x, ALPHA*x); p_ij = max(Ar_i*E_j, Br_i*F_j)
//   Ar = exp(x-m), Br = exp(ALPHA*x-m), E = exp(s2-8), F = exp(ALPHA*(s2-8)).
// K1: W->bf16 swizzled LDS (in-block), Wh MFMA, WhT stored in k3-native tile
//     order [b][c:16][oct:32][f:128][jo:8] bf16, plus s1, E, F.
// K3: BARRIER-FREE K-loop: B-frags read directly from global (L2-resident,
//     quad-contiguous 256B), P generated in A-frag layout, l via ones-column
//     MFMA, LDS used only for the epilogue reduce.

#define ALPHA 0.2f
#define NN 4096
#define FD 128

typedef __attribute__((ext_vector_type(8))) short s8v;     // 8 x bf16 raw bits
typedef __attribute__((ext_vector_type(4))) float f4v;     // MFMA C/D
typedef __attribute__((ext_vector_type(2))) unsigned int u2v;
typedef __attribute__((ext_vector_type(4))) unsigned int u4v;

__device__ __forceinline__ unsigned short f2bf(float x) {  // RNE float->bf16
  unsigned u = __float_as_uint(x);
  u += 0x7FFFu + ((u >> 16) & 1u);
  return (unsigned short)(u >> 16);
}
__device__ __forceinline__ void gl2lds16(const void* g, void* l) {
  __builtin_amdgcn_global_load_lds(
      (const __attribute__((address_space(1))) unsigned int*)g,
      (__attribute__((address_space(3))) unsigned int*)l, 16, 0, 0);
}

// ---------------- K1: Wh + tiled WhT + s1/E/F ----------------
// grid 256 x 256 thr (4 waves). b = blk>>6, j0 = (blk&63)<<6, wave w: 16 j.
// MFMA: C[m=j][n=f] = sum_i h[j][i] * W^T[f][i].
__global__ __launch_bounds__(256, 4) void k1_gemm(
    const float* __restrict__ h,            // [4][4096][128] f32
    const float* __restrict__ W,            // [128][128] f32, W[i][f]
    const float* __restrict__ a,            // [256] f32
    unsigned short* __restrict__ WhTt,      // tiled [4][16][32][128][8] bf16
    float* __restrict__ s1g,                // [4][4096]
    float* __restrict__ Eg,                 // [4][4096]
    float* __restrict__ Fg)                 // [4][4096]
{
  __shared__ __align__(16) unsigned char wls[32768];
  const int tid = threadIdx.x;
  const int b = blockIdx.x >> 6;
  const int j0 = (blockIdx.x & 63) << 6;

  // convert W -> swizzled bf16 W^T image in LDS:
  // (f,i) -> byte f*256 + (((i>>3)^(f&15))<<4) + (i&7)*2
#pragma unroll
  for (int it = 0; it < 16; ++it) {
    int cidx = it * 256 + tid;                 // 4096 chunks of 4 floats
    int i = cidx >> 5;
    int f0 = (cidx & 31) << 2;
    f4v v = *(const f4v*)(W + (size_t)cidx * 4);
#pragma unroll
    for (int e = 0; e < 4; ++e) {
      int f = f0 + e;
      int byte = f * 256 + (((i >> 3) ^ (f & 15)) << 4) + ((i & 7) << 1);
      *(unsigned short*)(wls + byte) = f2bf(v[e]);
    }
  }
  __syncthreads();

  const int w = tid >> 6, lane = tid & 63;
  const int quad = lane >> 4, lcol = lane & 15;
  const int jrow = j0 + 16 * w + lcol;      // A-frag m index

  f4v acc[8];
#pragma unroll
  for (int nt = 0; nt < 8; ++nt) acc[nt] = (f4v){0.f, 0.f, 0.f, 0.f};

#pragma unroll
  for (int kk = 0; kk < 4; ++kk) {
    const float* hp = h + (((size_t)(b * NN + jrow)) << 7) + (kk << 5) + (quad << 3);
    f4v v0 = *(const f4v*)hp;
    f4v v1 = *(const f4v*)(hp + 4);
    s8v af;
#pragma unroll
    for (int e = 0; e < 4; ++e) {
      af[e] = (short)f2bf(v0[e]);
      af[4 + e] = (short)f2bf(v1[e]);
    }
#pragma unroll
    for (int nt = 0; nt < 8; ++nt) {        // B = W^T[f][i] from swizzled LDS
      int f = 16 * nt + lcol;
      int slot = ((kk << 2) + quad) ^ (f & 15);
      s8v bfr = *(const s8v*)(wls + (f << 8) + (slot << 4));
      acc[nt] = __builtin_amdgcn_mfma_f32_16x16x32_bf16(af, bfr, acc[nt], 0, 0, 0);
    }
  }

  // s1/s2 dots over f (lane partials over its 8 f, reduce over lcol)
  float s1v[4] = {0, 0, 0, 0}, s2v[4] = {0, 0, 0, 0};
#pragma unroll
  for (int nt = 0; nt < 8; ++nt) {
    float a1 = a[16 * nt + lcol];
    float a2 = a[128 + 16 * nt + lcol];
#pragma unroll
    for (int r = 0; r < 4; ++r) {
      s1v[r] += acc[nt][r] * a1;
      s2v[r] += acc[nt][r] * a2;
    }
  }
#pragma unroll
  for (int r = 0; r < 4; ++r) {
#pragma unroll
    for (int d = 1; d < 16; d <<= 1) {
      s1v[r] += __shfl_xor(s1v[r], d, 64);
      s2v[r] += __shfl_xor(s2v[r], d, 64);
    }
  }
  if (lcol == 0) {
    int jb = b * NN + j0 + 16 * w + (quad << 2);
    *(f4v*)(s1g + jb) = (f4v){s1v[0], s1v[1], s1v[2], s1v[3]};
    f4v Ee, Ff;
#pragma unroll
    for (int r = 0; r < 4; ++r) {
      float d = s2v[r] - 8.0f;              // <= 0 given s2 <= 8
      Ee[r] = __expf(d);
      Ff[r] = __expf(ALPHA * d);
    }
    *(f4v*)(Eg + jb) = Ee;
    *(f4v*)(Fg + jb) = Ff;
  }

  // tiled WhT store: [b][c][oct][f][jo]; lane's 4 j are jo = (quad&1)*4 + r
  {
    const int c = j0 >> 8;
    const int octb = ((j0 & 255) >> 3) + 2 * w + (quad >> 1);
    const int eoff = (quad & 1) << 2;
#pragma unroll
    for (int nt = 0; nt < 8; ++nt) {
      int f = 16 * nt + lcol;
      unsigned u0 = __float_as_uint(acc[nt][0]) + 0x8000u;
      unsigned u1 = __float_as_uint(acc[nt][1]) + 0x8000u;
      unsigned u2 = __float_as_uint(acc[nt][2]) + 0x8000u;
      unsigned u3 = __float_as_uint(acc[nt][3]) + 0x8000u;
      u2v pk;
      pk[0] = (u0 >> 16) | (u1 & 0xFFFF0000u);
      pk[1] = (u2 >> 16) | (u3 & 0xFFFF0000u);
      size_t off = ((((size_t)(b * 16 + c) * 32 + octb) * 128 + f) << 3) + eoff;
      *(u2v*)(WhTt + off) = pk;
    }
  }
}

// ---------------- K3: fused softmax + P@Wh + ELU, barrier-free K-loop ----
// grid 256 x 512 thr (8 waves). b = blk>>6, 64-row i-tile. Wave kp owns
// j-local [32kp,32kp+32) of each 256-j chunk; mt=4 row-tiles per wave.
// B-frags straight from global (L2-hot, quad-contiguous 256B segments).
__global__ __launch_bounds__(512, 2) void k3_attn(
    const unsigned short* __restrict__ WhTt,  // [4][16][32][128][8] bf16
    const float* __restrict__ s1g,
    const float* __restrict__ Eg,
    const float* __restrict__ Fg,
    float* __restrict__ out)
{
  __shared__ __align__(16) unsigned char smem[33024]; // epilogue only
  const int tid = threadIdx.x;
  const int kp = tid >> 6, lane = tid & 63;
  const int quad = lane >> 4, lcol = lane & 15;
  const int b = blockIdx.x >> 6;
  const int i0 = (blockIdx.x & 63) << 6;
  const int oct = (kp << 2) + quad;         // j-octet this lane consumes

  float Ar[4], Br[4];
#pragma unroll
  for (int mt = 0; mt < 4; ++mt) {
    float x = s1g[b * NN + i0 + 16 * mt + lcol] + 8.0f;
    float m = fmaxf(x, ALPHA * x);          // >= row max of e
    Ar[mt] = __expf(x - m);
    Br[mt] = __expf(ALPHA * x - m);
  }

  f4v acc[4][8], accL[4];
#pragma unroll
  for (int mt = 0; mt < 4; ++mt) {
    accL[mt] = (f4v){0.f, 0.f, 0.f, 0.f};
#pragma unroll
    for (int nt = 0; nt < 8; ++nt) acc[mt][nt] = (f4v){0.f, 0.f, 0.f, 0.f};
  }
  s8v ones;
  {
    short o = (lcol == 0) ? (short)0x3F80 : (short)0;  // bf16 1.0 at n==0
#pragma unroll
    for (int t = 0; t < 8; ++t) ones[t] = o;
  }

  const unsigned short* whtb = WhTt + ((size_t)b << 19);  // 16*32*128*8 elems
  const float* Egb = Eg + b * NN;
  const float* Fgb = Fg + b * NN;
  const int jw = oct << 3;                  // j offset within chunk

  f4v Ec0 = *(const f4v*)(Egb + jw), Ec1 = *(const f4v*)(Egb + jw + 4);
  f4v Fc0 = *(const f4v*)(Fgb + jw), Fc1 = *(const f4v*)(Fgb + jw + 4);

  for (int c = 0; c < 16; ++c) {            // 16 chunks x 256 j, NO barriers
    // B-frag loads for chunk c (lane: 16B; quad: 256B contiguous)
    const unsigned short* tile = whtb + ((size_t)c << 15) + (oct << 10);
    s8v bfr[8];
#pragma unroll
    for (int nt = 0; nt < 8; ++nt)
      bfr[nt] = *(const s8v*)(tile + (((nt << 4) + lcol) << 3));

    // E/F prefetch for chunk c+1
    f4v En0, En1, Fn0, Fn1;
    if (c < 15) {
      int jg = ((c + 1) << 8) + jw;
      En0 = *(const f4v*)(Egb + jg); En1 = *(const f4v*)(Egb + jg + 4);
      Fn0 = *(const f4v*)(Fgb + jg); Fn1 = *(const f4v*)(Fgb + jg + 4);
    }

    float Ev[8] = {Ec0[0], Ec0[1], Ec0[2], Ec0[3], Ec1[0], Ec1[1], Ec1[2], Ec1[3]};
    float Fv[8] = {Fc0[0], Fc0[1], Fc0[2], Fc0[3], Fc1[0], Fc1[1], Fc1[2], Fc1[3]};

    s8v af[4];
#pragma unroll
    for (int mt = 0; mt < 4; ++mt) {        // P in A-frag layout
      float A = Ar[mt], Bc = Br[mt];
      u4v pk4;
#pragma unroll
      for (int t = 0; t < 8; t += 2) {
        float p0 = fmaxf(A * Ev[t], Bc * Fv[t]);
        float p1 = fmaxf(A * Ev[t + 1], Bc * Fv[t + 1]);
        unsigned u0 = __float_as_uint(p0) + 0x8000u;
        unsigned u1 = __float_as_uint(p1) + 0x8000u;
        pk4[t >> 1] = __builtin_amdgcn_perm(u1, u0, 0x07060302);
      }
      af[mt] = __builtin_bit_cast(s8v, pk4);
    }
#pragma unroll
    for (int nt = 0; nt < 8; ++nt)          // B-frags read ONCE, reused 4x
#pragma unroll
      for (int mt = 0; mt < 4; ++mt)
        acc[mt][nt] = __builtin_amdgcn_mfma_f32_16x16x32_bf16(af[mt], bfr[nt], acc[mt][nt], 0, 0, 0);
#pragma unroll
    for (int mt = 0; mt < 4; ++mt)          // l = sum_j p-hat (consistent)
      accL[mt] = __builtin_amdgcn_mfma_f32_16x16x32_bf16(af[mt], ones, accL[mt], 0, 0, 0);

    Ec0 = En0; Ec1 = En1; Fc0 = Fn0; Fc1 = Fn1;
  }

  // ---- epilogue: cross-wave reduce in LDS, softmax normalize, ELU ----
  float* hsum = (float*)smem;               // [64][128] f32, quad-swizzled
  float* l_red = (float*)(smem + 32768);    // [64]
#pragma unroll
  for (int t = 0; t < 4; ++t)
    *(f4v*)(hsum + tid * 16 + t * 4) = (f4v){0.f, 0.f, 0.f, 0.f};
  if (tid < 64) l_red[tid] = 0.f;
  __syncthreads();

#pragma unroll
  for (int mt = 0; mt < 4; ++mt) {
    if (lcol == 0) {
#pragma unroll
      for (int r = 0; r < 4; ++r)
        atomicAdd(&l_red[16 * mt + (quad << 2) + r], accL[mt][r]);
    }
#pragma unroll
    for (int nt = 0; nt < 8; ++nt)
#pragma unroll
      for (int r = 0; r < 4; ++r) {
        int row = 16 * mt + (quad << 2) + r;
        int f = (nt << 4) + lcol;
        int fx = (f + (quad << 3)) & 127;   // row-consistent bank swizzle
        atomicAdd(&hsum[(row << 7) + fx], acc[mt][nt][r]);
      }
  }
  __syncthreads();

  {
    int r = tid >> 3;                       // 64 rows, 8 thr/row, 16 f each
    int f0 = (tid & 7) << 4;
    int off = ((r >> 2) & 3) << 3;          // same swizzle as writes
    float il = 1.0f / l_red[r];             // l > 0 by construction
    size_t o = (((size_t)b * NN + i0 + r) << 7) + f0;
#pragma unroll
    for (int t = 0; t < 4; ++t) {
      int fx = (f0 + 4 * t + off) & 127;
      f4v v = *(const f4v*)(hsum + (r << 7) + fx);
      f4v ov;
#pragma unroll
      for (int e = 0; e < 4; ++e) {
        float x = v[e] * il;
        ov[e] = x > 0.f ? x : (__expf(x) - 1.f);  // elu
      }
      *(f4v*)(out + o + 4 * t) = ov;
    }
  }
}

extern "C" void kernel_launch(void* const* d_in, const int* in_sizes, int n_in,
                              void* d_out, int out_size, void* d_ws, size_t ws_size,
                              hipStream_t stream) {
  const float* h = (const float*)d_in[0];
  const float* W = (const float*)d_in[1];
  const float* a = (const float*)d_in[2];
  float* out = (float*)d_out;
  unsigned char* ws = (unsigned char*)d_ws;

  unsigned short* WhTt = (unsigned short*)ws;             // 4 MB tiled bf16
  float* s1g = (float*)(ws + 4194304);                    // 64 KB
  float* Eg  = (float*)(ws + 4259840);                    // 64 KB
  float* Fg  = (float*)(ws + 4325376);                    // 64 KB
  const size_t NEEDED = 4390912;
  if (ws_size < NEEDED) return;  // clean absmax-fail => ws too small

  hipLaunchKernelGGL(k1_gemm, dim3(256), dim3(256), 0, stream,
                     h, W, a, WhTt, s1g, Eg, Fg);
  hipLaunchKernelGGL(k3_attn, dim3(256), dim3(512), 0, stream,
                     WhTt, s1g, Eg, Fg, out);
}

// Round 7
// 176.434 us; speedup vs baseline: 1.0308x; 1.0308x over previous
//
#include <hip/hip_runtime.h>
#include <hip/hip_bf16.h>

// GraphAttentionLayer on MI355X. fp32 I/O, bf16 MFMA internally.
// e[b,i,j] = leakyrelu(s1_i + s2_j), softmax over j, out = elu(attn @ Wh).
// Bound M2_UB = 8 >= max s2 (s2 sigma ~0.9):
//   x_i = s1_i + 8; m_i = max(x, ALPHA*x); p_ij = max(Ar_i*E_j, Br_i*F_j)
//   Ar = exp(x-m), Br = exp(ALPHA*x-m), E = exp(s2-8), F = exp(ALPHA*(s2-8)).
// K1: W->bf16 swizzled LDS (in-block), Wh MFMA, WhT stored in k3-native tile
//     order [b][c:16][oct:32][f:128][jo:8] bf16, plus s1, E, F.
// K3: barrier-free K-loop, B-frags direct from global. NEW vs R6:
//     (1) per-block chunk STAGGER to kill the same-line multicast storm
//         (all blocks of a batch were reading identical L2 lines in lockstep
//         -> TCC serialized duplicate deliveries -> ~2 TB/s effective);
//     (2) XCD-aligned batch mapping (batch b on XCD pair {2b,2b+1}) so the
//         per-XCD L2 working set is 1 MB, requesters of a line co-XCD.

#define ALPHA 0.2f
#define NN 4096
#define FD 128

typedef __attribute__((ext_vector_type(8))) short s8v;     // 8 x bf16 raw bits
typedef __attribute__((ext_vector_type(4))) float f4v;     // MFMA C/D
typedef __attribute__((ext_vector_type(2))) unsigned int u2v;
typedef __attribute__((ext_vector_type(4))) unsigned int u4v;

__device__ __forceinline__ unsigned short f2bf(float x) {  // RNE float->bf16
  unsigned u = __float_as_uint(x);
  u += 0x7FFFu + ((u >> 16) & 1u);
  return (unsigned short)(u >> 16);
}

// ---------------- K1: Wh + tiled WhT + s1/E/F ----------------
// grid 256 x 256 thr (4 waves). b = blk>>6, j0 = (blk&63)<<6, wave w: 16 j.
// MFMA: C[m=j][n=f] = sum_i h[j][i] * W^T[f][i].
__global__ __launch_bounds__(256, 4) void k1_gemm(
    const float* __restrict__ h,            // [4][4096][128] f32
    const float* __restrict__ W,            // [128][128] f32, W[i][f]
    const float* __restrict__ a,            // [256] f32
    unsigned short* __restrict__ WhTt,      // tiled [4][16][32][128][8] bf16
    float* __restrict__ s1g,                // [4][4096]
    float* __restrict__ Eg,                 // [4][4096]
    float* __restrict__ Fg)                 // [4][4096]
{
  __shared__ __align__(16) unsigned char wls[32768];
  const int tid = threadIdx.x;
  const int b = blockIdx.x >> 6;
  const int j0 = (blockIdx.x & 63) << 6;

  // convert W -> swizzled bf16 W^T image in LDS:
  // (f,i) -> byte f*256 + (((i>>3)^(f&15))<<4) + (i&7)*2
#pragma unroll
  for (int it = 0; it < 16; ++it) {
    int cidx = it * 256 + tid;                 // 4096 chunks of 4 floats
    int i = cidx >> 5;
    int f0 = (cidx & 31) << 2;
    f4v v = *(const f4v*)(W + (size_t)cidx * 4);
#pragma unroll
    for (int e = 0; e < 4; ++e) {
      int f = f0 + e;
      int byte = f * 256 + (((i >> 3) ^ (f & 15)) << 4) + ((i & 7) << 1);
      *(unsigned short*)(wls + byte) = f2bf(v[e]);
    }
  }
  __syncthreads();

  const int w = tid >> 6, lane = tid & 63;
  const int quad = lane >> 4, lcol = lane & 15;
  const int jrow = j0 + 16 * w + lcol;      // A-frag m index

  f4v acc[8];
#pragma unroll
  for (int nt = 0; nt < 8; ++nt) acc[nt] = (f4v){0.f, 0.f, 0.f, 0.f};

#pragma unroll
  for (int kk = 0; kk < 4; ++kk) {
    const float* hp = h + (((size_t)(b * NN + jrow)) << 7) + (kk << 5) + (quad << 3);
    f4v v0 = *(const f4v*)hp;
    f4v v1 = *(const f4v*)(hp + 4);
    s8v af;
#pragma unroll
    for (int e = 0; e < 4; ++e) {
      af[e] = (short)f2bf(v0[e]);
      af[4 + e] = (short)f2bf(v1[e]);
    }
#pragma unroll
    for (int nt = 0; nt < 8; ++nt) {        // B = W^T[f][i] from swizzled LDS
      int f = 16 * nt + lcol;
      int slot = ((kk << 2) + quad) ^ (f & 15);
      s8v bfr = *(const s8v*)(wls + (f << 8) + (slot << 4));
      acc[nt] = __builtin_amdgcn_mfma_f32_16x16x32_bf16(af, bfr, acc[nt], 0, 0, 0);
    }
  }

  // s1/s2 dots over f (lane partials over its 8 f, reduce over lcol)
  float s1v[4] = {0, 0, 0, 0}, s2v[4] = {0, 0, 0, 0};
#pragma unroll
  for (int nt = 0; nt < 8; ++nt) {
    float a1 = a[16 * nt + lcol];
    float a2 = a[128 + 16 * nt + lcol];
#pragma unroll
    for (int r = 0; r < 4; ++r) {
      s1v[r] += acc[nt][r] * a1;
      s2v[r] += acc[nt][r] * a2;
    }
  }
#pragma unroll
  for (int r = 0; r < 4; ++r) {
#pragma unroll
    for (int d = 1; d < 16; d <<= 1) {
      s1v[r] += __shfl_xor(s1v[r], d, 64);
      s2v[r] += __shfl_xor(s2v[r], d, 64);
    }
  }
  if (lcol == 0) {
    int jb = b * NN + j0 + 16 * w + (quad << 2);
    *(f4v*)(s1g + jb) = (f4v){s1v[0], s1v[1], s1v[2], s1v[3]};
    f4v Ee, Ff;
#pragma unroll
    for (int r = 0; r < 4; ++r) {
      float d = s2v[r] - 8.0f;              // <= 0 given s2 <= 8
      Ee[r] = __expf(d);
      Ff[r] = __expf(ALPHA * d);
    }
    *(f4v*)(Eg + jb) = Ee;
    *(f4v*)(Fg + jb) = Ff;
  }

  // tiled WhT store: [b][c][oct][f][jo]; lane's 4 j are jo = (quad&1)*4 + r
  {
    const int c = j0 >> 8;
    const int octb = ((j0 & 255) >> 3) + 2 * w + (quad >> 1);
    const int eoff = (quad & 1) << 2;
#pragma unroll
    for (int nt = 0; nt < 8; ++nt) {
      int f = 16 * nt + lcol;
      unsigned u0 = __float_as_uint(acc[nt][0]) + 0x8000u;
      unsigned u1 = __float_as_uint(acc[nt][1]) + 0x8000u;
      unsigned u2 = __float_as_uint(acc[nt][2]) + 0x8000u;
      unsigned u3 = __float_as_uint(acc[nt][3]) + 0x8000u;
      u2v pk;
      pk[0] = (u0 >> 16) | (u1 & 0xFFFF0000u);
      pk[1] = (u2 >> 16) | (u3 & 0xFFFF0000u);
      size_t off = ((((size_t)(b * 16 + c) * 32 + octb) * 128 + f) << 3) + eoff;
      *(u2v*)(WhTt + off) = pk;
    }
  }
}

// ---------------- K3: fused softmax + P@Wh + ELU, barrier-free K-loop ----
// grid 256 x 512 thr (8 waves). XCD-aligned: batch b on XCD pair {2b,2b+1}.
// Wave kp owns j-local [32kp,32kp+32) of each 256-j chunk; mt=4 row-tiles.
// Per-block chunk stagger decorrelates same-line L2 requests across blocks.
__global__ __launch_bounds__(512, 2) void k3_attn(
    const unsigned short* __restrict__ WhTt,  // [4][16][32][128][8] bf16
    const float* __restrict__ s1g,
    const float* __restrict__ Eg,
    const float* __restrict__ Fg,
    float* __restrict__ out)
{
  __shared__ __align__(16) unsigned char smem[33024]; // epilogue only
  const int tid = threadIdx.x;
  const int kp = tid >> 6, lane = tid & 63;
  const int quad = lane >> 4, lcol = lane & 15;
  // XCD-aligned mapping (blk%8 ~ XCD on MI355X round-robin heuristic)
  const int b = (blockIdx.x & 7) >> 1;              // batch on XCD pair
  const int i0 = ((((blockIdx.x & 1) << 5) | (blockIdx.x >> 3))) << 6;
  const int c0 = (blockIdx.x >> 3) & 15;            // chunk stagger
  const int oct = (kp << 2) + quad;         // j-octet this lane consumes

  float Ar[4], Br[4];
#pragma unroll
  for (int mt = 0; mt < 4; ++mt) {
    float x = s1g[b * NN + i0 + 16 * mt + lcol] + 8.0f;
    float m = fmaxf(x, ALPHA * x);          // >= row max of e
    Ar[mt] = __expf(x - m);
    Br[mt] = __expf(ALPHA * x - m);
  }

  f4v acc[4][8], accL[4];
#pragma unroll
  for (int mt = 0; mt < 4; ++mt) {
    accL[mt] = (f4v){0.f, 0.f, 0.f, 0.f};
#pragma unroll
    for (int nt = 0; nt < 8; ++nt) acc[mt][nt] = (f4v){0.f, 0.f, 0.f, 0.f};
  }
  s8v ones;
  {
    short o = (lcol == 0) ? (short)0x3F80 : (short)0;  // bf16 1.0 at n==0
#pragma unroll
    for (int t = 0; t < 8; ++t) ones[t] = o;
  }

  const unsigned short* whtb = WhTt + ((size_t)b << 19);  // 16*32*128*8 elems
  const float* Egb = Eg + b * NN;
  const float* Fgb = Fg + b * NN;
  const int jw = oct << 3;                  // j offset within chunk

  f4v Ec0 = *(const f4v*)(Egb + (c0 << 8) + jw);
  f4v Ec1 = *(const f4v*)(Egb + (c0 << 8) + jw + 4);
  f4v Fc0 = *(const f4v*)(Fgb + (c0 << 8) + jw);
  f4v Fc1 = *(const f4v*)(Fgb + (c0 << 8) + jw + 4);

  for (int cc = 0; cc < 16; ++cc) {         // staggered chunk order
    const int c = (cc + c0) & 15;           // j-sum is order-invariant
    // B-frag loads for chunk c (lane: 16B; quad: 256B contiguous)
    const unsigned short* tile = whtb + ((size_t)c << 15) + (oct << 10);
    s8v bfr[8];
#pragma unroll
    for (int nt = 0; nt < 8; ++nt)
      bfr[nt] = *(const s8v*)(tile + (((nt << 4) + lcol) << 3));

    // E/F prefetch for next chunk
    f4v En0, En1, Fn0, Fn1;
    if (cc < 15) {
      int jg = (((cc + 1 + c0) & 15) << 8) + jw;
      En0 = *(const f4v*)(Egb + jg); En1 = *(const f4v*)(Egb + jg + 4);
      Fn0 = *(const f4v*)(Fgb + jg); Fn1 = *(const f4v*)(Fgb + jg + 4);
    }

    float Ev[8] = {Ec0[0], Ec0[1], Ec0[2], Ec0[3], Ec1[0], Ec1[1], Ec1[2], Ec1[3]};
    float Fv[8] = {Fc0[0], Fc0[1], Fc0[2], Fc0[3], Fc1[0], Fc1[1], Fc1[2], Fc1[3]};

    s8v af[4];
#pragma unroll
    for (int mt = 0; mt < 4; ++mt) {        // P in A-frag layout
      float A = Ar[mt], Bc = Br[mt];
      u4v pk4;
#pragma unroll
      for (int t = 0; t < 8; t += 2) {
        float p0 = fmaxf(A * Ev[t], Bc * Fv[t]);
        float p1 = fmaxf(A * Ev[t + 1], Bc * Fv[t + 1]);
        unsigned u0 = __float_as_uint(p0) + 0x8000u;
        unsigned u1 = __float_as_uint(p1) + 0x8000u;
        pk4[t >> 1] = __builtin_amdgcn_perm(u1, u0, 0x07060302);
      }
      af[mt] = __builtin_bit_cast(s8v, pk4);
    }
#pragma unroll
    for (int nt = 0; nt < 8; ++nt)          // B-frags read ONCE, reused 4x
#pragma unroll
      for (int mt = 0; mt < 4; ++mt)
        acc[mt][nt] = __builtin_amdgcn_mfma_f32_16x16x32_bf16(af[mt], bfr[nt], acc[mt][nt], 0, 0, 0);
#pragma unroll
    for (int mt = 0; mt < 4; ++mt)          // l = sum_j p-hat (consistent)
      accL[mt] = __builtin_amdgcn_mfma_f32_16x16x32_bf16(af[mt], ones, accL[mt], 0, 0, 0);

    Ec0 = En0; Ec1 = En1; Fc0 = Fn0; Fc1 = Fn1;
  }

  // ---- epilogue: cross-wave reduce in LDS, softmax normalize, ELU ----
  float* hsum = (float*)smem;               // [64][128] f32, quad-swizzled
  float* l_red = (float*)(smem + 32768);    // [64]
#pragma unroll
  for (int t = 0; t < 4; ++t)
    *(f4v*)(hsum + tid * 16 + t * 4) = (f4v){0.f, 0.f, 0.f, 0.f};
  if (tid < 64) l_red[tid] = 0.f;
  __syncthreads();

#pragma unroll
  for (int mt = 0; mt < 4; ++mt) {
    if (lcol == 0) {
#pragma unroll
      for (int r = 0; r < 4; ++r)
        atomicAdd(&l_red[16 * mt + (quad << 2) + r], accL[mt][r]);
    }
#pragma unroll
    for (int nt = 0; nt < 8; ++nt)
#pragma unroll
      for (int r = 0; r < 4; ++r) {
        int row = 16 * mt + (quad << 2) + r;
        int f = (nt << 4) + lcol;
        int fx = (f + (quad << 3)) & 127;   // row-consistent bank swizzle
        atomicAdd(&hsum[(row << 7) + fx], acc[mt][nt][r]);
      }
  }
  __syncthreads();

  {
    int r = tid >> 3;                       // 64 rows, 8 thr/row, 16 f each
    int f0 = (tid & 7) << 4;
    int off = ((r >> 2) & 3) << 3;          // same swizzle as writes
    float il = 1.0f / l_red[r];             // l > 0 by construction
    size_t o = (((size_t)b * NN + i0 + r) << 7) + f0;
#pragma unroll
    for (int t = 0; t < 4; ++t) {
      int fx = (f0 + 4 * t + off) & 127;
      f4v v = *(const f4v*)(hsum + (r << 7) + fx);
      f4v ov;
#pragma unroll
      for (int e = 0; e < 4; ++e) {
        float x = v[e] * il;
        ov[e] = x > 0.f ? x : (__expf(x) - 1.f);  // elu
      }
      *(f4v*)(out + o + 4 * t) = ov;
    }
  }
}

extern "C" void kernel_launch(void* const* d_in, const int* in_sizes, int n_in,
                              void* d_out, int out_size, void* d_ws, size_t ws_size,
                              hipStream_t stream) {
  const float* h = (const float*)d_in[0];
  const float* W = (const float*)d_in[1];
  const float* a = (const float*)d_in[2];
  float* out = (float*)d_out;
  unsigned char* ws = (unsigned char*)d_ws;

  unsigned short* WhTt = (unsigned short*)ws;             // 4 MB tiled bf16
  float* s1g = (float*)(ws + 4194304);                    // 64 KB
  float* Eg  = (float*)(ws + 4259840);                    // 64 KB
  float* Fg  = (float*)(ws + 4325376);                    // 64 KB
  const size_t NEEDED = 4390912;
  if (ws_size < NEEDED) return;  // clean absmax-fail => ws too small

  hipLaunchKernelGGL(k1_gemm, dim3(256), dim3(256), 0, stream,
                     h, W, a, WhTt, s1g, Eg, Fg);
  hipLaunchKernelGGL(k3_attn, dim3(256), dim3(512), 0, stream,
                     WhTt, s1g, Eg, Fg, out);
}